// Round 7
// baseline (1880.871 us; speedup 1.0000x reference)
//
#include <hip/hip_runtime.h>
#include <math.h>

#define NB 32
#define NT 512
#define NDIN 1024
#define NDCB 256
#define NKCB 8192
#define NHMID 512
#define NROWS (NB*NT)   // 16384

typedef _Float16 half2_t __attribute__((ext_vector_type(2)));
typedef _Float16 f16x8 __attribute__((ext_vector_type(8)));
typedef __attribute__((ext_vector_type(8))) short bf16x8;
typedef __attribute__((ext_vector_type(8))) unsigned short u16x8;
typedef __attribute__((ext_vector_type(4))) float f32x4;

__device__ __forceinline__ unsigned short f2bf(float x) {
    unsigned int u = __float_as_uint(x);
    return (unsigned short)((u + 0x7fffu + ((u >> 16) & 1u)) >> 16);   // RNE
}

__device__ __forceinline__ half2_t h2of(unsigned int u) {
    return __builtin_bit_cast(half2_t, u);
}

// Register pin: forces the value to exist in a VGPR at this point; being volatile and
// outside the scan loop, the compiler cannot re-materialize (sink) the producing load —
// it must keep the value resident or spill it VISIBLY (localSizeBytes).  Counters r6:
// without pins the backend sank the whole weight preload into the loop (VGPR=68, zero
// spill, ~786KB/step re-read from L2 -> same 655us wall as the spill path).
__device__ __forceinline__ void pin_h2(half2_t& v) {
    unsigned int t = __builtin_bit_cast(unsigned int, v);
    asm volatile("" : "+v"(t));
    v = __builtin_bit_cast(half2_t, t);
}

#if __has_builtin(__builtin_amdgcn_fdot2)
__device__ __forceinline__ float dot2f(half2_t a, half2_t b, float c) {
    return __builtin_amdgcn_fdot2(a, b, c, false);
}
#else
__device__ __forceinline__ float dot2f(half2_t a, half2_t b, float c) {
    return fmaf((float)a[0], (float)b[0], fmaf((float)a[1], (float)b[1], c));
}
#endif

// ---------------- fp64-accumulate tiled GEMM: C = act(A(MxK) * B(NxK)^T + bias) ----------------
// fp32 in/out, fp64 accumulation: output = fl(exact), the canonical fp32 result.  [LOCKED numerics]
template<bool RELU>
__global__ __launch_bounds__(256) void gemm_nt_f64_kernel(
    const float* __restrict__ A, const float* __restrict__ Bm,
    const float* __restrict__ bias, float* __restrict__ C,
    int M, int N, int K)
{
    __shared__ double a_s[16*64];
    __shared__ double b_s[16*64];
    const int tid = threadIdx.x;
    const int bn0 = blockIdx.x * 64;
    const int bm0 = blockIdx.y * 64;
    const int lr = tid >> 2;          // 0..63
    const int kq = (tid & 3) << 2;    // 0,4,8,12
    const int tx = tid & 15, ty = tid >> 4;
    double acc[4][4] = {};
    const float* Ap = A + (size_t)(bm0 + lr) * K + kq;
    const float* Bp = Bm + (size_t)(bn0 + lr) * K + kq;
    for (int kt = 0; kt < K; kt += 16) {
        float4 a = *(const float4*)(Ap + kt);
        float4 b = *(const float4*)(Bp + kt);
        __syncthreads();
        a_s[(kq+0)*64+lr] = (double)a.x; a_s[(kq+1)*64+lr] = (double)a.y;
        a_s[(kq+2)*64+lr] = (double)a.z; a_s[(kq+3)*64+lr] = (double)a.w;
        b_s[(kq+0)*64+lr] = (double)b.x; b_s[(kq+1)*64+lr] = (double)b.y;
        b_s[(kq+2)*64+lr] = (double)b.z; b_s[(kq+3)*64+lr] = (double)b.w;
        __syncthreads();
        #pragma unroll
        for (int kk = 0; kk < 16; kk++) {
            double aa[4], bb[4];
            #pragma unroll
            for (int u = 0; u < 4; u++) { aa[u] = a_s[kk*64 + ty*4 + u]; bb[u] = b_s[kk*64 + tx*4 + u]; }
            #pragma unroll
            for (int i = 0; i < 4; i++)
                #pragma unroll
                for (int j = 0; j < 4; j++)
                    acc[i][j] = fma(aa[i], bb[j], acc[i][j]);
        }
    }
    const float4 b4 = *(const float4*)&bias[bn0 + tx*4];
    const double bc[4] = {(double)b4.x, (double)b4.y, (double)b4.z, (double)b4.w};
    #pragma unroll
    for (int i = 0; i < 4; i++) {
        float o[4];
        #pragma unroll
        for (int j = 0; j < 4; j++) {
            double v = acc[i][j] + bc[j];
            if (RELU) v = fmax(v, 0.0);
            o[j] = (float)v;
        }
        *(float4*)&C[(size_t)(bm0 + ty*4 + i)*N + bn0 + tx*4] =
            make_float4(o[0], o[1], o[2], o[3]);
    }
}

// ---------------- conv1d k=3 SAME, fp64 accumulation ----------------  [LOCKED numerics]
__global__ __launch_bounds__(256) void conv3_f64_kernel(
    const float* __restrict__ H2, const float* __restrict__ W3,
    const float* __restrict__ bias, float* __restrict__ F)
{
    __shared__ double a_s[16*68];       // [k][local row], local l <-> global bm0-1+l
    __shared__ double b_s[3][16*64];
    const int tid = threadIdx.x;
    const int bn0 = blockIdx.x * 64;
    const int bm0 = blockIdx.y * 64;
    const int lr = tid >> 2;
    const int kq = (tid & 3) << 2;
    const int tx = tid & 15, ty = tid >> 4;
    const int tmod = bm0 & (NT-1);
    const bool has_top = (tmod != 0);
    const bool has_bot = (tmod + 64 < NT);
    double acc[4][4] = {};
    for (int kt = 0; kt < NDCB; kt += 16) {
        float4 a = make_float4(0.f,0.f,0.f,0.f);
        if (lr >= 1 || has_top)
            a = *(const float4*)&H2[(size_t)(bm0 - 1 + lr)*NDCB + kt + kq];
        float4 e = make_float4(0.f,0.f,0.f,0.f);
        int l2 = 0, kq2 = 0;
        if (tid < 8) {
            l2 = 64 + (tid >> 2); kq2 = (tid & 3) << 2;
            if (l2 == 64 || has_bot)
                e = *(const float4*)&H2[(size_t)(bm0 - 1 + l2)*NDCB + kt + kq2];
        }
        float4 w[3];
        #pragma unroll
        for (int s = 0; s < 3; s++)
            w[s] = *(const float4*)&W3[(size_t)s*65536 + (size_t)(bn0 + lr)*NDCB + kt + kq];
        __syncthreads();
        a_s[(kq+0)*68+lr]=(double)a.x; a_s[(kq+1)*68+lr]=(double)a.y;
        a_s[(kq+2)*68+lr]=(double)a.z; a_s[(kq+3)*68+lr]=(double)a.w;
        if (tid < 8) {
            a_s[(kq2+0)*68+l2]=(double)e.x; a_s[(kq2+1)*68+l2]=(double)e.y;
            a_s[(kq2+2)*68+l2]=(double)e.z; a_s[(kq2+3)*68+l2]=(double)e.w;
        }
        #pragma unroll
        for (int s = 0; s < 3; s++) {
            b_s[s][(kq+0)*64+lr]=(double)w[s].x; b_s[s][(kq+1)*64+lr]=(double)w[s].y;
            b_s[s][(kq+2)*64+lr]=(double)w[s].z; b_s[s][(kq+3)*64+lr]=(double)w[s].w;
        }
        __syncthreads();
        #pragma unroll
        for (int kk = 0; kk < 16; kk++) {
            double aa[6];
            #pragma unroll
            for (int u = 0; u < 6; u++) aa[u] = a_s[kk*68 + ty*4 + u];
            #pragma unroll
            for (int s = 0; s < 3; s++) {
                double bb[4];
                #pragma unroll
                for (int u = 0; u < 4; u++) bb[u] = b_s[s][kk*64 + tx*4 + u];
                #pragma unroll
                for (int i = 0; i < 4; i++)
                    #pragma unroll
                    for (int j = 0; j < 4; j++)
                        acc[i][j] = fma(aa[i+s], bb[j], acc[i][j]);
            }
        }
    }
    const float4 b4 = *(const float4*)&bias[bn0 + tx*4];
    const double bc[4] = {(double)b4.x, (double)b4.y, (double)b4.z, (double)b4.w};
    #pragma unroll
    for (int i = 0; i < 4; i++) {
        const size_t base = (size_t)(bm0 + ty*4 + i)*NDCB + bn0 + tx*4;
        *(float4*)&F[base] = make_float4((float)(acc[i][0]+bc[0]), (float)(acc[i][1]+bc[1]),
                                         (float)(acc[i][2]+bc[2]), (float)(acc[i][3]+bc[3]));
    }
}

// ---------------- VQ: bf16 MFMA prefilter + canonical-fp32-quantized argmin on near-ties ----
// Prefilter error sigma ~3e-7 vs score spread ~2e-4; tol 1e-5 (~24 sigma); near-ties
// rescored canonically.  [LOCKED numerics on the rescore path]
__global__ __launch_bounds__(512) void vq_kernel(
    const float* __restrict__ F, const float* __restrict__ CB,
    const unsigned short* __restrict__ CBH,
    const float* __restrict__ cnorm, float* __restrict__ idx_out,
    float* __restrict__ qout, float* __restrict__ msd_acc)
{
    __shared__ unsigned short a_bf[64*256];   // 32 KB, swizzled bf16 F-tile
    __shared__ unsigned short b_bf[128*256];  // 64 KB, swizzled bf16 CB-chunk
    __shared__ float cn_s[128];
    __shared__ float red_v[64*64];            // top-2 per (row, entry); reused for msd reduce
    __shared__ int   red_i[64*64];
    __shared__ int   bests[64];
    __shared__ int   cand[64][12];
    __shared__ int   ccnt[64];
    const int tid = threadIdx.x;
    const int m0 = blockIdx.x * 64;

    // ---- stage A once: F[m0..m0+64) x 256 -> bf16, swizzled ----
    #pragma unroll
    for (int u = 0; u < 4; u++) {
        int e = tid + u*512;                 // < 2048
        int row = e >> 5, c = e & 31;
        const float* src = &F[(size_t)(m0+row)*NDCB + c*8];
        float4 f0 = *(const float4*)src;
        float4 f1 = *(const float4*)(src+4);
        u16x8 p;
        p[0]=f2bf(f0.x); p[1]=f2bf(f0.y); p[2]=f2bf(f0.z); p[3]=f2bf(f0.w);
        p[4]=f2bf(f1.x); p[5]=f2bf(f1.y); p[6]=f2bf(f1.z); p[7]=f2bf(f1.w);
        *(u16x8*)((char*)a_bf + row*512 + ((c*16) ^ ((row&7)<<4))) = p;
    }

    // wave w: rows 16*(w&3), cols 64*(w>>2) of each 64x128 chunk
    const int w = tid >> 6, lane = tid & 63;
    const int l15 = lane & 15, kg = lane >> 4;
    const int rbase = (w & 3) << 4, cbase = (w >> 2) << 6;
    const char* aP = (const char*)a_bf + (size_t)(rbase + l15)*512;
    const char* bP = (const char*)b_bf + (size_t)(cbase + l15)*512;
    const int swz = (lane & 7) << 4;

    float mv1[4], mv2[4]; int mi1[4], mi2[4];
    #pragma unroll
    for (int i = 0; i < 4; i++) { mv1[i]=3.0e38f; mv2[i]=3.0e38f; mi1[i]=0x7fffffff; mi2[i]=0x7fffffff; }

    for (int n0 = 0; n0 < NKCB; n0 += 128) {
        __syncthreads();                      // previous chunk's MFMA reads done
        #pragma unroll
        for (int u = 0; u < 8; u++) {
            int e = tid + u*512;              // < 4096
            int row = e >> 5, c = e & 31;
            u16x8 v = *(const u16x8*)&CBH[(size_t)(n0+row)*NDCB + c*8];
            *(u16x8*)((char*)b_bf + row*512 + ((c*16) ^ ((row&7)<<4))) = v;
        }
        if (tid < 128) cn_s[tid] = cnorm[n0 + tid];
        __syncthreads();
        f32x4 acc[4] = {{0.f,0.f,0.f,0.f},{0.f,0.f,0.f,0.f},{0.f,0.f,0.f,0.f},{0.f,0.f,0.f,0.f}};
        #pragma unroll
        for (int kt = 0; kt < 8; kt++) {
            const int ko = (kt*64 + kg*16) ^ swz;
            bf16x8 av = *(const bf16x8*)(aP + ko);
            #pragma unroll
            for (int f = 0; f < 4; f++) {
                bf16x8 bv = *(const bf16x8*)(bP + f*8192 + ko);
                acc[f] = __builtin_amdgcn_mfma_f32_16x16x32_bf16(av, bv, acc[f], 0, 0, 0);
            }
        }
        // epilogue: s = cn - 2*dot ; per-lane top-2.  C layout: col=lane&15, row=(lane>>4)*4+reg.
        #pragma unroll
        for (int f = 0; f < 4; f++) {
            const int col = n0 + cbase + f*16 + l15;
            const float cnv = cn_s[cbase + f*16 + l15];
            #pragma unroll
            for (int i = 0; i < 4; i++) {
                float s = fmaf(-2.0f, acc[f][i], cnv);
                if (s < mv1[i]) { mv2[i]=mv1[i]; mi2[i]=mi1[i]; mv1[i]=s; mi1[i]=col; }
                else if (s < mv2[i]) { mv2[i]=s; mi2[i]=col; }
            }
        }
    }
    #pragma unroll
    for (int i = 0; i < 4; i++) {
        const int row = rbase + kg*4 + i;
        const int eb  = (w>>2)*32 + l15*2;
        red_v[row*64 + eb]   = mv1[i]; red_i[row*64 + eb]   = mi1[i];
        red_v[row*64 + eb+1] = mv2[i]; red_i[row*64 + eb+1] = mi2[i];
    }
    __syncthreads();
    if (tid < 64) {
        float bv = 3.0e38f; int bi = 0x7fffffff;
        for (int e = 0; e < 64; e++) {
            float v = red_v[tid*64 + e]; int ii = red_i[tid*64 + e];
            if (v < bv || (v == bv && ii < bi)) { bv = v; bi = ii; }
        }
        int cnt = 0;
        for (int e = 0; e < 64; e++) {
            if (red_v[tid*64 + e] < bv + 1.0e-5f) {
                if (cnt < 12) cand[tid][cnt] = red_i[tid*64 + e];
                cnt++;
            }
        }
        bests[tid] = bi;
        ccnt[tid] = (cnt > 12) ? 12 : cnt;
    }
    __syncthreads();
    // Canonical fp32-quantized rescore of near-tie rows (one wave per row, round-robin).
    {
        const int wid = tid >> 6, lane2 = tid & 63;
        for (int r = wid; r < 64; r += 8) {
            const int nc = ccnt[r];
            if (nc < 2) continue;
            double sf = 0.0;
            #pragma unroll
            for (int u = 0; u < 4; u++) {
                double fv = (double)F[(size_t)(m0+r)*NDCB + lane2*4 + u];
                sf = fma(fv, fv, sf);
            }
            #pragma unroll
            for (int off = 32; off > 0; off >>= 1) sf += __shfl_down(sf, off);
            const float sf32 = (float)sf;          // valid on lane 0
            float bd2 = 0.0f; int bidx = 0x7fffffff;
            for (int c = 0; c < nc; c++) {
                const int k = cand[r][c];
                double g = 0.0;
                #pragma unroll
                for (int u = 0; u < 4; u++) {
                    double cv = (double)CB[(size_t)k*NDCB + lane2*4 + u];
                    double fv = (double)F[(size_t)(m0+r)*NDCB + lane2*4 + u];
                    g = fma(cv, fv, g);
                }
                #pragma unroll
                for (int off = 32; off > 0; off >>= 1) g += __shfl_down(g, off);
                if (lane2 == 0) {
                    const float G32 = (float)g;
                    const float t  = sf32 - 2.0f*G32;
                    const float d2 = t + cnorm[k];
                    if (c == 0 || d2 < bd2 || (d2 == bd2 && k < bidx)) { bd2 = d2; bidx = k; }
                }
            }
            if (lane2 == 0) bests[r] = bidx;
        }
    }
    __syncthreads();
    if (tid < 64) idx_out[m0 + tid] = (float)bests[tid];
    float lsum = 0.0f;
    #pragma unroll
    for (int s = 0; s < 8; s++) {
        int e = tid + s*512;
        int row = e >> 6, kqe = (e & 63) << 2;
        float4 q = *(const float4*)&CB[(size_t)bests[row]*NDCB + kqe];
        float4 f = *(const float4*)&F[(size_t)(m0+row)*NDCB + kqe];
        float dx=f.x-q.x, dy=f.y-q.y, dz=f.z-q.z, dw=f.w-q.w;
        lsum += dx*dx + dy*dy + dz*dz + dw*dw;
        *(float4*)&qout[(size_t)(m0+row)*NDCB + kqe] = q;
    }
    red_v[tid] = lsum;
    __syncthreads();
    for (int off = 256; off > 0; off >>= 1) {
        if (tid < off) red_v[tid] += red_v[tid + off];
        __syncthreads();
    }
    if (tid == 0) atomicAdd(msd_acc, red_v[0]);
}

// ---------------- xproj: f16 MFMA GEMM (feeds GRU/context_loss, 2% threshold) ----------------
__global__ __launch_bounds__(512) void xproj_mfma_kernel(
    const float* __restrict__ Q, const unsigned short* __restrict__ WIHH,
    const float* __restrict__ bias, float* __restrict__ C)
{
    __shared__ unsigned short a_h[64*256];    // 32 KB, swizzled f16 (q * 8192)
    __shared__ unsigned short b_h[128*256];   // 64 KB, swizzled f16 wih chunk
    const int tid = threadIdx.x;
    const int m0 = blockIdx.x * 64;

    #pragma unroll
    for (int u = 0; u < 4; u++) {
        int e = tid + u*512;                 // < 2048
        int row = e >> 5, c = e & 31;
        const float* src = &Q[(size_t)(m0+row)*NDCB + c*8];
        float4 f0 = *(const float4*)src;
        float4 f1 = *(const float4*)(src+4);
        f16x8 p;
        p[0]=(_Float16)(f0.x*8192.0f); p[1]=(_Float16)(f0.y*8192.0f);
        p[2]=(_Float16)(f0.z*8192.0f); p[3]=(_Float16)(f0.w*8192.0f);
        p[4]=(_Float16)(f1.x*8192.0f); p[5]=(_Float16)(f1.y*8192.0f);
        p[6]=(_Float16)(f1.z*8192.0f); p[7]=(_Float16)(f1.w*8192.0f);
        *(f16x8*)((char*)a_h + row*512 + ((c*16) ^ ((row&7)<<4))) = p;
    }

    const int w = tid >> 6, lane = tid & 63;
    const int l15 = lane & 15, kg = lane >> 4;
    const int rbase = (w & 3) << 4, cbase = (w >> 2) << 6;
    const char* aP = (const char*)a_h + (size_t)(rbase + l15)*512;
    const char* bP = (const char*)b_h + (size_t)(cbase + l15)*512;
    const int swz = (lane & 7) << 4;

    for (int n0 = 0; n0 < 768; n0 += 128) {
        __syncthreads();
        #pragma unroll
        for (int u = 0; u < 8; u++) {
            int e = tid + u*512;              // < 4096
            int row = e >> 5, c = e & 31;
            u16x8 v = *(const u16x8*)&WIHH[(size_t)(n0+row)*NDCB + c*8];
            *(u16x8*)((char*)b_h + row*512 + ((c*16) ^ ((row&7)<<4))) = v;
        }
        __syncthreads();
        f32x4 acc[4] = {{0.f,0.f,0.f,0.f},{0.f,0.f,0.f,0.f},{0.f,0.f,0.f,0.f},{0.f,0.f,0.f,0.f}};
        #pragma unroll
        for (int kt = 0; kt < 8; kt++) {
            const int ko = (kt*64 + kg*16) ^ swz;
            f16x8 av = *(const f16x8*)(aP + ko);
            #pragma unroll
            for (int f = 0; f < 4; f++) {
                f16x8 bv = *(const f16x8*)(bP + f*8192 + ko);
                acc[f] = __builtin_amdgcn_mfma_f32_16x16x32_f16(av, bv, acc[f], 0, 0, 0);
            }
        }
        // C layout: col=lane&15, row=(lane>>4)*4+reg
        #pragma unroll
        for (int f = 0; f < 4; f++) {
            const int col = n0 + cbase + f*16 + l15;
            const float bv = bias[col];
            #pragma unroll
            for (int i = 0; i < 4; i++) {
                const int row = m0 + rbase + kg*4 + i;
                C[(size_t)row*768 + col] = fmaf(acc[f][i], 1.0f/8192.0f, bv);
            }
        }
    }
}

// ================= GRU scan =================================================================
// r6 post-mortem: (a) gru_body_768's preload loop ran k<32 -> wg[64..127] UNINITIALIZED ->
// garbage h -> absmax 0.25 (ctx ~ mean(h^2)).  Fixed: k<64.  (b) Without explicit pins the
// backend SINKS loop-invariant weight loads into the scan loop (r6: VGPR=68, no spill,
// ~786KB/step L2 re-read -> same 655us wall as spilling).  pin_h2() blocks sinking; the
// selector gates on numRegs (sink detector) + scores spill via localSizeBytes.

// ---- body B (FIXED): 768 threads, full-row ownership.  Thread (g=tid>>8, j=tid&255)
// computes the complete 256-wide dot for gate row g*256+j: 128 weight half2 + ~27 working
// regs (~155) -> fits the 168-VGPR budget of waves_per_eu(3,3) (12-wave block max tier).
__device__ __forceinline__ void gru_body_768(
    const float* __restrict__ XP, const float* __restrict__ WHH,
    const float* __restrict__ bhh, const float* __restrict__ F,
    float* __restrict__ ctx_acc)
{
    __shared__ float sg[3][256];    // r,z: gh+x ; n: gh only
    __shared__ float xs[256];       // xn stash
    __shared__ uint4 hpk[2][32];
    __shared__ float red[256];
    const int tid = threadIdx.x;    // < 768
    const int b = blockIdx.x;
    const int g = tid >> 8;         // 0..2
    const int j = tid & 255;
    half2_t wg[128];                // row g*256+j, cols 2m..2m+1  (ALL 256 cols)
    {
        const float* rp = WHH + ((size_t)g*256 + j)*256;
        #pragma unroll
        for (int k = 0; k < 64; k++) {          // FIX r6: was k<32 (half the row!)
            float4 v = *(const float4*)(rp + 4*k);
            wg[2*k+0] = (half2_t){(_Float16)v.x, (_Float16)v.y};
            wg[2*k+1] = (half2_t){(_Float16)v.z, (_Float16)v.w};
        }
    }
    #pragma unroll
    for (int m = 0; m < 128; m++) pin_h2(wg[m]);   // block load-sinking
    if (tid < 64) hpk[tid >> 5][tid & 31] = make_uint4(0u, 0u, 0u, 0u);
    const float bbg = bhh[g*256 + j];
    const float* xq = XP + (size_t)b*NT*768 + g*256 + j;   // += 768/step
    const float* fq = F  + (size_t)b*NT*NDCB + NDCB + j;   // g==0 only; += 256/step
    float hprev = 0.0f, lsum = 0.0f;
    __syncthreads();
    int cur = 0;
    for (int t = 0; t < NT-1; t++) {
        float xg = *xq; xq += 768;
        float fv = 0.f;
        if (g == 0) { fv = *fq; fq += 256; }   // waves 0..3, wave-uniform
        float a0 = 0.f, a1 = 0.f;
        #pragma unroll
        for (int kk = 0; kk < 32; kk += 2) {
            uint4 hp0 = hpk[cur][kk];
            uint4 hp1 = hpk[cur][kk+1];
            a0 = dot2f(wg[4*kk+0], h2of(hp0.x), a0); a1 = dot2f(wg[4*kk+1], h2of(hp0.y), a1);
            a0 = dot2f(wg[4*kk+2], h2of(hp0.z), a0); a1 = dot2f(wg[4*kk+3], h2of(hp0.w), a1);
            a0 = dot2f(wg[4*kk+4], h2of(hp1.x), a0); a1 = dot2f(wg[4*kk+5], h2of(hp1.y), a1);
            a0 = dot2f(wg[4*kk+6], h2of(hp1.z), a0); a1 = dot2f(wg[4*kk+7], h2of(hp1.w), a1);
        }
        float gh = a0 + a1 + bbg;
        if (g == 2) { sg[2][j] = gh; xs[j] = xg; }   // n gate: n=tanh(xn + r*ghn)
        else        { sg[g][j] = gh + xg; }
        __syncthreads();
        if (tid < 256) {
            float r = 1.0f/(1.0f + __expf(-sg[0][j]));
            float z = 1.0f/(1.0f + __expf(-sg[1][j]));
            float v = fmaf(r, sg[2][j], xs[j]);
            v = fminf(fmaxf(v, -12.0f), 12.0f);
            float ev = __expf(-2.0f*v);
            float n = (1.0f - ev)/(1.0f + ev);
            float hnew = (1.0f - z)*n + z*hprev;
            float d = hnew - fv;
            lsum = fmaf(d, d, lsum);
            float nb = __shfl_down(hnew, 1);
            if (!(j & 1)) {
                half2_t p; p[0] = (_Float16)hnew; p[1] = (_Float16)nb;
                ((unsigned int*)&hpk[cur ^ 1][0])[j >> 1] = __builtin_bit_cast(unsigned int, p);
            }
            hprev = hnew;
        }
        __syncthreads();
        cur ^= 1;
    }
    if (tid < 256) red[j] = lsum;
    __syncthreads();
    for (int off = 128; off > 0; off >>= 1) {
        if (tid < off) red[tid] += red[tid + off];
        __syncthreads();
    }
    if (tid == 0) atomicAdd(ctx_acc, red[0]);
}

__global__ __attribute__((amdgpu_flat_work_group_size(768, 768), amdgpu_waves_per_eu(3, 3)))
void gru_v1(const float* __restrict__ XP, const float* __restrict__ WHH,
            const float* __restrict__ bhh, const float* __restrict__ F,
            float* __restrict__ ctx_acc)
{ gru_body_768(XP, WHH, bhh, F, ctx_acc); }

__global__ __launch_bounds__(768)
void gru_v2(const float* __restrict__ XP, const float* __restrict__ WHH,
            const float* __restrict__ bhh, const float* __restrict__ F,
            float* __restrict__ ctx_acc)
{ gru_body_768(XP, WHH, bhh, F, ctx_acc); }

// ---- body A: 1024 threads, 96 weight half2/thread (+ pins).  Budget 128 at 4 waves/EU;
// need ~124 -> small/zero spill expected.
__device__ __forceinline__ void gru_body_1024(
    const float* __restrict__ XP, const float* __restrict__ WHH,
    const float* __restrict__ bhh, const float* __restrict__ F,
    float* __restrict__ ctx_acc)
{
    __shared__ float part[3][4][256];      // 12 KB
    __shared__ uint4 hpk[2][32];
    __shared__ float red[256];
    __shared__ float bbs[3][256];
    const int tid = threadIdx.x;
    const int b = blockIdx.x;
    const int j = tid & 255;
    const int q = tid >> 8;                // 0..3
    half2_t wr[32], wz[32], wn[32];        // 96 VGPRs
    {
        const float* rp = WHH + (size_t)j*256 + q*64;
        #pragma unroll
        for (int k = 0; k < 16; k++) {
            float4 vr = *(const float4*)(rp + 4*k);
            float4 vz = *(const float4*)(rp + 65536 + 4*k);
            float4 vn = *(const float4*)(rp + 131072 + 4*k);
            wr[2*k+0] = (half2_t){(_Float16)vr.x, (_Float16)vr.y};
            wr[2*k+1] = (half2_t){(_Float16)vr.z, (_Float16)vr.w};
            wz[2*k+0] = (half2_t){(_Float16)vz.x, (_Float16)vz.y};
            wz[2*k+1] = (half2_t){(_Float16)vz.z, (_Float16)vz.w};
            wn[2*k+0] = (half2_t){(_Float16)vn.x, (_Float16)vn.y};
            wn[2*k+1] = (half2_t){(_Float16)vn.z, (_Float16)vn.w};
        }
    }
    #pragma unroll
    for (int m = 0; m < 32; m++) { pin_h2(wr[m]); pin_h2(wz[m]); pin_h2(wn[m]); }
    if (tid < 64) hpk[tid >> 5][tid & 31] = make_uint4(0u, 0u, 0u, 0u);
    if (tid < 256) { bbs[0][j] = bhh[j]; bbs[1][j] = bhh[256+j]; bbs[2][j] = bhh[512+j]; }
    const float* xq = XP + (size_t)b*NT*768 + j;
    const float* fq = F  + (size_t)b*NT*NDCB + NDCB + j;
    float hprev = 0.0f, lsum = 0.0f;
    __syncthreads();
    int cur = 0;
    for (int t = 0; t < NT-1; t++) {
        float xr = 0.f, xz = 0.f, xn = 0.f, fv = 0.f;
        if (tid < 256) {
            xr = xq[0]; xz = xq[256]; xn = xq[512];
            fv = *fq;
            xq += 768; fq += 256;
        }
        float a0=0.f, c0=0.f, a1=0.f, c1=0.f, a2=0.f, c2=0.f;
        #pragma unroll
        for (int kk = 0; kk < 8; kk++) {
            uint4 hp = hpk[cur][q*8 + kk];
            half2_t h0 = h2of(hp.x), h1 = h2of(hp.y), h2 = h2of(hp.z), h3 = h2of(hp.w);
            a0 = dot2f(wr[4*kk+0], h0, a0); c0 = dot2f(wr[4*kk+1], h1, c0);
            a1 = dot2f(wz[4*kk+0], h0, a1); c1 = dot2f(wz[4*kk+1], h1, c1);
            a2 = dot2f(wn[4*kk+0], h0, a2); c2 = dot2f(wn[4*kk+1], h1, c2);
            a0 = dot2f(wr[4*kk+2], h2, a0); c0 = dot2f(wr[4*kk+3], h3, c0);
            a1 = dot2f(wz[4*kk+2], h2, a1); c1 = dot2f(wz[4*kk+3], h3, c1);
            a2 = dot2f(wn[4*kk+2], h2, a2); c2 = dot2f(wn[4*kk+3], h3, c2);
        }
        part[0][q][j] = a0 + c0; part[1][q][j] = a1 + c1; part[2][q][j] = a2 + c2;
        __syncthreads();
        if (tid < 256) {
            float ghr = part[0][0][j] + part[0][1][j] + part[0][2][j] + part[0][3][j] + bbs[0][j];
            float ghz = part[1][0][j] + part[1][1][j] + part[1][2][j] + part[1][3][j] + bbs[1][j];
            float ghn = part[2][0][j] + part[2][1][j] + part[2][2][j] + part[2][3][j] + bbs[2][j];
            float r = 1.0f/(1.0f + __expf(-(xr + ghr)));
            float z = 1.0f/(1.0f + __expf(-(xz + ghz)));
            float v = fmaf(r, ghn, xn);
            v = fminf(fmaxf(v, -12.0f), 12.0f);
            float ev = __expf(-2.0f*v);
            float n = (1.0f - ev)/(1.0f + ev);
            float hnew = (1.0f - z)*n + z*hprev;
            float d = hnew - fv;
            lsum = fmaf(d, d, lsum);
            float nb = __shfl_down(hnew, 1);
            if (!(j & 1)) {
                half2_t p; p[0] = (_Float16)hnew; p[1] = (_Float16)nb;
                ((unsigned int*)&hpk[cur ^ 1][0])[j >> 1] = __builtin_bit_cast(unsigned int, p);
            }
            hprev = hnew;
        }
        __syncthreads();
        cur ^= 1;
    }
    if (tid < 256) red[j] = lsum;
    __syncthreads();
    for (int off = 128; off > 0; off >>= 1) {
        if (tid < off) red[tid] += red[tid + off];
        __syncthreads();
    }
    if (tid == 0) atomicAdd(ctx_acc, red[0]);
}

__global__ __launch_bounds__(1024, 1)
void gru_w1(const float* __restrict__ XP, const float* __restrict__ WHH,
            const float* __restrict__ bhh, const float* __restrict__ F,
            float* __restrict__ ctx_acc)
{ gru_body_1024(XP, WHH, bhh, F, ctx_acc); }

// ---- body C: 512-thread fallback (proven absmax 0.0; 128 VGPR + spill replay, ~655 us) -----
__global__ __launch_bounds__(512)
void gru_c(const float* __restrict__ XP, const float* __restrict__ WHH,
           const float* __restrict__ bhh, const float* __restrict__ F,
           float* __restrict__ ctx_acc)
{
    __shared__ float part[3][2][256];
    __shared__ uint4 hpk[2][32];
    __shared__ float red[256];
    const int tid = threadIdx.x;
    const int b = blockIdx.x;
    const int j = tid & 255;
    const int q = tid >> 8;           // 0..1
    half2_t wr[64], wz[64], wn[64];
    {
        const float* rp = WHH + (size_t)j*256 + q*128;
        #pragma unroll
        for (int k = 0; k < 32; k++) {
            float4 vr = *(const float4*)(rp + 4*k);
            float4 vz = *(const float4*)(rp + 65536 + 4*k);
            float4 vn = *(const float4*)(rp + 131072 + 4*k);
            wr[2*k+0] = (half2_t){(_Float16)vr.x, (_Float16)vr.y};
            wr[2*k+1] = (half2_t){(_Float16)vr.z, (_Float16)vr.w};
            wz[2*k+0] = (half2_t){(_Float16)vz.x, (_Float16)vz.y};
            wz[2*k+1] = (half2_t){(_Float16)vz.z, (_Float16)vz.w};
            wn[2*k+0] = (half2_t){(_Float16)vn.x, (_Float16)vn.y};
            wn[2*k+1] = (half2_t){(_Float16)vn.z, (_Float16)vn.w};
        }
    }
    if (tid < 64) hpk[tid >> 5][tid & 31] = make_uint4(0u, 0u, 0u, 0u);
    const float bb0 = bhh[j], bb1 = bhh[256+j], bb2 = bhh[512+j];
    const float* xpb = XP + (size_t)b*NT*768;
    const float* fb  = F  + (size_t)b*NT*NDCB;
    float hprev = 0.0f, lsum = 0.0f;
    __syncthreads();
    int cur = 0;
    for (int t = 0; t < NT-1; t++) {
        float xr = 0.f, xz = 0.f, xn = 0.f, fv = 0.f;
        if (tid < 256) {
            const float* xp = xpb + (size_t)t*768;
            xr = xp[j]; xz = xp[256+j]; xn = xp[512+j];
            fv = fb[(size_t)(t+1)*NDCB + j];
        }
        float a0=0.f, c0=0.f, a1=0.f, c1=0.f, a2=0.f, c2=0.f;
        #pragma unroll
        for (int kk = 0; kk < 16; kk++) {
            uint4 hp = hpk[cur][q*16 + kk];
            half2_t h0 = h2of(hp.x), h1 = h2of(hp.y), h2 = h2of(hp.z), h3 = h2of(hp.w);
            a0 = dot2f(wr[4*kk+0], h0, a0); c0 = dot2f(wr[4*kk+1], h1, c0);
            a1 = dot2f(wz[4*kk+0], h0, a1); c1 = dot2f(wz[4*kk+1], h1, c1);
            a2 = dot2f(wn[4*kk+0], h0, a2); c2 = dot2f(wn[4*kk+1], h1, c2);
            a0 = dot2f(wr[4*kk+2], h2, a0); c0 = dot2f(wr[4*kk+3], h3, c0);
            a1 = dot2f(wz[4*kk+2], h2, a1); c1 = dot2f(wz[4*kk+3], h3, c1);
            a2 = dot2f(wn[4*kk+2], h2, a2); c2 = dot2f(wn[4*kk+3], h3, c2);
        }
        part[0][q][j] = a0 + c0; part[1][q][j] = a1 + c1; part[2][q][j] = a2 + c2;
        __syncthreads();
        if (tid < 256) {
            float ghr = part[0][0][j] + part[0][1][j] + bb0;
            float ghz = part[1][0][j] + part[1][1][j] + bb1;
            float ghn = part[2][0][j] + part[2][1][j] + bb2;
            float r = 1.0f/(1.0f + __expf(-(xr + ghr)));
            float z = 1.0f/(1.0f + __expf(-(xz + ghz)));
            float v = fmaf(r, ghn, xn);
            v = fminf(fmaxf(v, -12.0f), 12.0f);
            float ev = __expf(-2.0f*v);
            float n = (1.0f - ev)/(1.0f + ev);
            float hnew = (1.0f - z)*n + z*hprev;
            float d = hnew - fv;
            lsum = fmaf(d, d, lsum);
            float nb = __shfl_down(hnew, 1);
            if (!(j & 1)) {
                half2_t p; p[0] = (_Float16)hnew; p[1] = (_Float16)nb;
                ((unsigned int*)&hpk[cur ^ 1][0])[j >> 1] = __builtin_bit_cast(unsigned int, p);
            }
            hprev = hnew;
        }
        __syncthreads();
        cur ^= 1;
    }
    if (tid < 256) red[j] = lsum;
    __syncthreads();
    for (int off = 128; off > 0; off >>= 1) {
        if (tid < off) red[tid] += red[tid + off];
        __syncthreads();
    }
    if (tid == 0) atomicAdd(ctx_acc, red[0]);
}

// ---------------- small prep kernels ----------------
__global__ __launch_bounds__(256) void prep_kernel(
    const float* __restrict__ conv_w, float* __restrict__ w3,
    const float* __restrict__ wih, unsigned short* __restrict__ wihh,
    float* __restrict__ accv)
{
    int e = blockIdx.x*256 + threadIdx.x;     // < 196608
    if (e == 0) { accv[0] = 0.0f; accv[1] = 0.0f; }
    {   // w3[k][c][i] = conv_w[c][i][k]
        int k = e >> 16;
        int r = e & 65535;
        int c = r >> 8, i = r & 255;
        w3[e] = conv_w[(size_t)c*768 + i*3 + k];
    }
    {   // wih f32 -> f16 bits (768*256 = 196608 elements, exactly this grid)
        _Float16 h = (_Float16)wih[e];
        wihh[e] = __builtin_bit_cast(unsigned short, h);
    }
}

// codebook fp32 -> bf16 (RNE), for the MFMA prefilter
__global__ __launch_bounds__(256) void cb2bf_kernel(
    const float* __restrict__ cb, unsigned short* __restrict__ cbh)
{
    int e = (blockIdx.x*256 + threadIdx.x) * 4;   // 2,097,152 elems / 4
    float4 v = *(const float4*)&cb[e];
    unsigned short p0 = f2bf(v.x), p1 = f2bf(v.y), p2 = f2bf(v.z), p3 = f2bf(v.w);
    unsigned long long pk = (unsigned long long)p0 | ((unsigned long long)p1 << 16)
                          | ((unsigned long long)p2 << 32) | ((unsigned long long)p3 << 48);
    *(unsigned long long*)&cbh[e] = pk;
}

// s_c = fl32(exact sum c^2) via fp64   [LOCKED numerics]
__global__ __launch_bounds__(64) void cnorm_kernel(
    const float* __restrict__ CB, float* __restrict__ cn)
{
    const int k = blockIdx.x;
    const int lane = threadIdx.x;
    float4 v = *(const float4*)&CB[(size_t)k*NDCB + lane*4];
    double s = (double)v.x*(double)v.x + (double)v.y*(double)v.y
             + (double)v.z*(double)v.z + (double)v.w*(double)v.w;
    #pragma unroll
    for (int off = 32; off > 0; off >>= 1) s += __shfl_down(s, off);
    if (lane == 0) cn[k] = (float)s;
}

__global__ void finalize_kernel(const float* __restrict__ acc, float* __restrict__ out)
{
    if (threadIdx.x == 0) {
        float msd = acc[0] * (1.0f/4194304.0f);   // mean over 32*512*256
        float ctx = acc[1] * (1.0f/4184064.0f);   // mean over 32*511*256
        out[0] = msd;                 // commitment_loss
        out[1] = msd;                 // codebook_loss (same forward value)
        out[2] = ctx;                 // context_loss
        out[3] = 1.25f*msd + 0.1f*ctx; // vq_loss
    }
}

extern "C" void kernel_launch(void* const* d_in, const int* in_sizes, int n_in,
                              void* d_out, int out_size, void* d_ws, size_t ws_size,
                              hipStream_t stream) {
    const float* x      = (const float*)d_in[0];
    const float* w1     = (const float*)d_in[1];
    const float* b1     = (const float*)d_in[2];
    const float* w2     = (const float*)d_in[3];
    const float* b2     = (const float*)d_in[4];
    const float* conv_w = (const float*)d_in[5];
    const float* conv_b = (const float*)d_in[6];
    const float* cb     = (const float*)d_in[7];
    const float* wih    = (const float*)d_in[8];
    const float* whh    = (const float*)d_in[9];
    const float* bih    = (const float*)d_in[10];
    const float* bhh    = (const float*)d_in[11];
    float* out = (float*)d_out;

    // workspace layout (regions re-used once dead):
    //   [0,        16.7M)  feat  (fp32)          conv -> gru
    //   [16.7M,    50.3M)  h1    (fp32)          gemm1 -> gemm2
    //   [16.7M,    67.1M)  xproj (fp32, 50.3MB)  gemm3 -> gru   (overlays dead h1+h2)
    //   [50.3M,    67.1M)  h2    (fp32)          gemm2 -> conv
    //   [50.3M,    54.5M)  cbh   (bf16, 4MB)     cb2bf -> vq    (overlays dead h2)
    //   [67.1M, ...]       cn / w3 / wihh / accv
    char* ws = (char*)d_ws;
    float*  feat   = (float*)(ws + 0);
    float*  h1     = (float*)(ws + 16777216);
    float*  xproj  = (float*)(ws + 16777216);
    float*  h2     = (float*)(ws + 50331648);
    unsigned short* cbh = (unsigned short*)(ws + 50331648);
    float*  cn     = (float*)(ws + 67108864);
    float*  w3     = (float*)(ws + 67141632);
    unsigned short* wihh = (unsigned short*)(ws + 67928064);   // 393216 B (old wht slot)
    float*  accv   = (float*)(ws + 68714496);

    float* idx_out = out;                   // 16384 indices (as float)
    float* qout    = out + 16384;           // 4,194,304 quantized
    float* louts   = out + 16384 + 4194304; // 4 scalars

    // GRU shell selection (host-side query, cached, capture-safe).
    // score = base_cyc/step + spill_replay (5 cyc per KB*thread of localSizeBytes;
    // calibrated: gru_c = 1650 + 548B*512*5/1024 ~= 3020 vs measured 3050 cyc/step).
    // numRegs gate: with pins, resident weights REQUIRE >= minreg arch VGPRs; a lower
    // count means the backend defeated residency some other way -> model invalid -> skip.
    static int gsel = -1;
    if (gsel < 0) {
        struct Cand { const void* f; long thr; long base; long minreg; };
        const Cand cands[3] = {
            { reinterpret_cast<const void*>(gru_v1),  768, 1300, 120 },
            { reinterpret_cast<const void*>(gru_v2),  768, 1300, 120 },
            { reinterpret_cast<const void*>(gru_w1), 1024, 1400,  90 },
        };
        long best = 3050;      // gru_c measured cyc/step
        gsel = 3;
        for (int i = 0; i < 3; i++) {
            hipFuncAttributes fa;
            if (hipFuncGetAttributes(&fa, cands[i].f) != hipSuccess) continue;
            if (fa.numRegs < cands[i].minreg) continue;
            long score = cands[i].base + (long)fa.localSizeBytes * cands[i].thr * 5 / 1024;
            if (score < best) { best = score; gsel = i; }
        }
    }

    prep_kernel<<<768, 256, 0, stream>>>(conv_w, w3, wih, wihh, accv);
    cnorm_kernel<<<NKCB, 64, 0, stream>>>(cb, cn);
    gemm_nt_f64_kernel<true ><<<dim3(NHMID/64, NROWS/64), 256, 0, stream>>>(x,  w1, b1, h1, NROWS, NHMID, NDIN);
    gemm_nt_f64_kernel<true ><<<dim3(NDCB/64,  NROWS/64), 256, 0, stream>>>(h1, w2, b2, h2, NROWS, NDCB, NHMID);
    conv3_f64_kernel<<<dim3(NDCB/64, NROWS/64), 256, 0, stream>>>(h2, w3, conv_b, feat);
    cb2bf_kernel<<<2048, 256, 0, stream>>>(cb, cbh);   // after conv3: overlays dead h2
    vq_kernel<<<NROWS/64, 512, 0, stream>>>(feat, cb, cbh, cn, idx_out, qout, accv);
    xproj_mfma_kernel<<<NROWS/64, 512, 0, stream>>>(qout, wihh, bih, xproj);
    if (gsel == 0)      gru_v1<<<NB,  768, 0, stream>>>(xproj, whh, bhh, feat, accv + 1);
    else if (gsel == 1) gru_v2<<<NB,  768, 0, stream>>>(xproj, whh, bhh, feat, accv + 1);
    else if (gsel == 2) gru_w1<<<NB, 1024, 0, stream>>>(xproj, whh, bhh, feat, accv + 1);
    else                gru_c<<<NB,  512, 0, stream>>>(xproj, whh, bhh, feat, accv + 1);
    finalize_kernel<<<1, 64, 0, stream>>>(accv, louts);
}

// Round 8
// 1623.550 us; speedup vs baseline: 1.1585x; 1.1585x over previous
//
#include <hip/hip_runtime.h>
#include <math.h>

#define NB 32
#define NT 512
#define NDIN 1024
#define NDCB 256
#define NKCB 8192
#define NHMID 512
#define NROWS (NB*NT)   // 16384

typedef _Float16 half2_t __attribute__((ext_vector_type(2)));
typedef _Float16 f16x8 __attribute__((ext_vector_type(8)));
typedef __attribute__((ext_vector_type(8))) short bf16x8;
typedef __attribute__((ext_vector_type(8))) unsigned short u16x8;
typedef __attribute__((ext_vector_type(4))) float f32x4;
typedef __attribute__((ext_vector_type(4))) double f64x4;

__device__ __forceinline__ unsigned short f2bf(float x) {
    unsigned int u = __float_as_uint(x);
    return (unsigned short)((u + 0x7fffu + ((u >> 16) & 1u)) >> 16);   // RNE
}

__device__ __forceinline__ half2_t h2of(unsigned int u) {
    return __builtin_bit_cast(half2_t, u);
}

#if __has_builtin(__builtin_amdgcn_fdot2)
__device__ __forceinline__ float dot2f(half2_t a, half2_t b, float c) {
    return __builtin_amdgcn_fdot2(a, b, c, false);
}
#else
__device__ __forceinline__ float dot2f(half2_t a, half2_t b, float c) {
    return fmaf((float)a[0], (float)b[0], fmaf((float)a[1], (float)b[1], c));
}
#endif

// ---------------- fp64-accumulate tiled GEMM: C = act(A(MxK) * B(NxK)^T + bias) ----------------
// fp32 in/out, fp64 accumulation: output = fl(exact), the canonical fp32 result.  [LOCKED numerics]
// r8: inner product moved from v_fma_f64 (256 issue slots/thread/K16) to v_mfma_f64_16x16x4
// (16 instr/wave/K16, 2048 FLOP each).  fp64-sum order changes are invisible after the fp32
// cast except on ~2^-26-probability rounding boundaries (<1 element expected pipeline-wide).
#if __has_builtin(__builtin_amdgcn_mfma_f64_16x16x4f64)
template<bool RELU>
__global__ __launch_bounds__(256) void gemm_nt_f64_kernel(
    const float* __restrict__ A, const float* __restrict__ Bm,
    const float* __restrict__ bias, float* __restrict__ C,
    int M, int N, int K)
{
    __shared__ double a_s[16*64];   // [k][row]
    __shared__ double b_s[16*64];   // [k][col]
    const int tid = threadIdx.x;
    const int bn0 = blockIdx.x * 64;
    const int bm0 = blockIdx.y * 64;
    const int lr = tid >> 2;          // 0..63
    const int kq = (tid & 3) << 2;    // 0,4,8,12
    const int lane = tid & 63, w = tid >> 6;
    const int l15 = lane & 15, kg = lane >> 4;   // kg: k within quad / row-group in D
    const int rbase = w << 4;                     // wave w owns rows rbase..rbase+16
    f64x4 acc[4] = {};                            // 4 col-tiles of 16
    const float* Ap = A + (size_t)(bm0 + lr) * K + kq;
    const float* Bp = Bm + (size_t)(bn0 + lr) * K + kq;
    for (int kt = 0; kt < K; kt += 16) {
        float4 a = *(const float4*)(Ap + kt);
        float4 b = *(const float4*)(Bp + kt);
        __syncthreads();
        a_s[(kq+0)*64+lr] = (double)a.x; a_s[(kq+1)*64+lr] = (double)a.y;
        a_s[(kq+2)*64+lr] = (double)a.z; a_s[(kq+3)*64+lr] = (double)a.w;
        b_s[(kq+0)*64+lr] = (double)b.x; b_s[(kq+1)*64+lr] = (double)b.y;
        b_s[(kq+2)*64+lr] = (double)b.z; b_s[(kq+3)*64+lr] = (double)b.w;
        __syncthreads();
        #pragma unroll
        for (int kk = 0; kk < 4; kk++) {          // 4 K-quads of 4
            const double av = a_s[(kk*4 + kg)*64 + rbase + l15];   // A[row=l15][k=kg]
            #pragma unroll
            for (int ct = 0; ct < 4; ct++) {
                const double bv = b_s[(kk*4 + kg)*64 + ct*16 + l15]; // B^T[k=kg][col=l15]
                acc[ct] = __builtin_amdgcn_mfma_f64_16x16x4f64(av, bv, acc[ct], 0, 0, 0);
            }
        }
    }
    // D layout (16x16 family, dtype-independent): col = lane&15, row = (lane>>4)*4 + i
    #pragma unroll
    for (int ct = 0; ct < 4; ct++) {
        const int col = bn0 + ct*16 + l15;
        const double bc = (double)bias[col];
        #pragma unroll
        for (int i = 0; i < 4; i++) {
            double v = acc[ct][i] + bc;
            if (RELU) v = fmax(v, 0.0);
            C[(size_t)(bm0 + rbase + kg*4 + i)*N + col] = (float)v;
        }
    }
}
#else
template<bool RELU>
__global__ __launch_bounds__(256) void gemm_nt_f64_kernel(
    const float* __restrict__ A, const float* __restrict__ Bm,
    const float* __restrict__ bias, float* __restrict__ C,
    int M, int N, int K)
{
    __shared__ double a_s[16*64];
    __shared__ double b_s[16*64];
    const int tid = threadIdx.x;
    const int bn0 = blockIdx.x * 64;
    const int bm0 = blockIdx.y * 64;
    const int lr = tid >> 2;
    const int kq = (tid & 3) << 2;
    const int tx = tid & 15, ty = tid >> 4;
    double acc[4][4] = {};
    const float* Ap = A + (size_t)(bm0 + lr) * K + kq;
    const float* Bp = Bm + (size_t)(bn0 + lr) * K + kq;
    for (int kt = 0; kt < K; kt += 16) {
        float4 a = *(const float4*)(Ap + kt);
        float4 b = *(const float4*)(Bp + kt);
        __syncthreads();
        a_s[(kq+0)*64+lr] = (double)a.x; a_s[(kq+1)*64+lr] = (double)a.y;
        a_s[(kq+2)*64+lr] = (double)a.z; a_s[(kq+3)*64+lr] = (double)a.w;
        b_s[(kq+0)*64+lr] = (double)b.x; b_s[(kq+1)*64+lr] = (double)b.y;
        b_s[(kq+2)*64+lr] = (double)b.z; b_s[(kq+3)*64+lr] = (double)b.w;
        __syncthreads();
        #pragma unroll
        for (int kk = 0; kk < 16; kk++) {
            double aa[4], bb[4];
            #pragma unroll
            for (int u = 0; u < 4; u++) { aa[u] = a_s[kk*64 + ty*4 + u]; bb[u] = b_s[kk*64 + tx*4 + u]; }
            #pragma unroll
            for (int i = 0; i < 4; i++)
                #pragma unroll
                for (int j = 0; j < 4; j++)
                    acc[i][j] = fma(aa[i], bb[j], acc[i][j]);
        }
    }
    const float4 b4 = *(const float4*)&bias[bn0 + tx*4];
    const double bc[4] = {(double)b4.x, (double)b4.y, (double)b4.z, (double)b4.w};
    #pragma unroll
    for (int i = 0; i < 4; i++) {
        float o[4];
        #pragma unroll
        for (int j = 0; j < 4; j++) {
            double v = acc[i][j] + bc[j];
            if (RELU) v = fmax(v, 0.0);
            o[j] = (float)v;
        }
        *(float4*)&C[(size_t)(bm0 + ty*4 + i)*N + bn0 + tx*4] =
            make_float4(o[0], o[1], o[2], o[3]);
    }
}
#endif

// ---------------- conv1d k=3 SAME, fp64 accumulation ----------------  [LOCKED numerics]
__global__ __launch_bounds__(256) void conv3_f64_kernel(
    const float* __restrict__ H2, const float* __restrict__ W3,
    const float* __restrict__ bias, float* __restrict__ F)
{
    __shared__ double a_s[16*68];       // [k][local row], local l <-> global bm0-1+l
    __shared__ double b_s[3][16*64];
    const int tid = threadIdx.x;
    const int bn0 = blockIdx.x * 64;
    const int bm0 = blockIdx.y * 64;
    const int lr = tid >> 2;
    const int kq = (tid & 3) << 2;
    const int tx = tid & 15, ty = tid >> 4;
    const int tmod = bm0 & (NT-1);
    const bool has_top = (tmod != 0);
    const bool has_bot = (tmod + 64 < NT);
    double acc[4][4] = {};
    for (int kt = 0; kt < NDCB; kt += 16) {
        float4 a = make_float4(0.f,0.f,0.f,0.f);
        if (lr >= 1 || has_top)
            a = *(const float4*)&H2[(size_t)(bm0 - 1 + lr)*NDCB + kt + kq];
        float4 e = make_float4(0.f,0.f,0.f,0.f);
        int l2 = 0, kq2 = 0;
        if (tid < 8) {
            l2 = 64 + (tid >> 2); kq2 = (tid & 3) << 2;
            if (l2 == 64 || has_bot)
                e = *(const float4*)&H2[(size_t)(bm0 - 1 + l2)*NDCB + kt + kq2];
        }
        float4 w[3];
        #pragma unroll
        for (int s = 0; s < 3; s++)
            w[s] = *(const float4*)&W3[(size_t)s*65536 + (size_t)(bn0 + lr)*NDCB + kt + kq];
        __syncthreads();
        a_s[(kq+0)*68+lr]=(double)a.x; a_s[(kq+1)*68+lr]=(double)a.y;
        a_s[(kq+2)*68+lr]=(double)a.z; a_s[(kq+3)*68+lr]=(double)a.w;
        if (tid < 8) {
            a_s[(kq2+0)*68+l2]=(double)e.x; a_s[(kq2+1)*68+l2]=(double)e.y;
            a_s[(kq2+2)*68+l2]=(double)e.z; a_s[(kq2+3)*68+l2]=(double)e.w;
        }
        #pragma unroll
        for (int s = 0; s < 3; s++) {
            b_s[s][(kq+0)*64+lr]=(double)w[s].x; b_s[s][(kq+1)*64+lr]=(double)w[s].y;
            b_s[s][(kq+2)*64+lr]=(double)w[s].z; b_s[s][(kq+3)*64+lr]=(double)w[s].w;
        }
        __syncthreads();
        #pragma unroll
        for (int kk = 0; kk < 16; kk++) {
            double aa[6];
            #pragma unroll
            for (int u = 0; u < 6; u++) aa[u] = a_s[kk*68 + ty*4 + u];
            #pragma unroll
            for (int s = 0; s < 3; s++) {
                double bb[4];
                #pragma unroll
                for (int u = 0; u < 4; u++) bb[u] = b_s[s][kk*64 + tx*4 + u];
                #pragma unroll
                for (int i = 0; i < 4; i++)
                    #pragma unroll
                    for (int j = 0; j < 4; j++)
                        acc[i][j] = fma(aa[i+s], bb[j], acc[i][j]);
            }
        }
    }
    const float4 b4 = *(const float4*)&bias[bn0 + tx*4];
    const double bc[4] = {(double)b4.x, (double)b4.y, (double)b4.z, (double)b4.w};
    #pragma unroll
    for (int i = 0; i < 4; i++) {
        const size_t base = (size_t)(bm0 + ty*4 + i)*NDCB + bn0 + tx*4;
        *(float4*)&F[base] = make_float4((float)(acc[i][0]+bc[0]), (float)(acc[i][1]+bc[1]),
                                         (float)(acc[i][2]+bc[2]), (float)(acc[i][3]+bc[3]));
    }
}

// ---------------- VQ: bf16 MFMA prefilter + canonical-fp32-quantized argmin on near-ties ----
// Prefilter error sigma ~3e-7 vs score spread ~2e-4; tol 1e-5 (~24 sigma); near-ties
// rescored canonically.  [LOCKED numerics on the rescore path]
__global__ __launch_bounds__(512) void vq_kernel(
    const float* __restrict__ F, const float* __restrict__ CB,
    const unsigned short* __restrict__ CBH,
    const float* __restrict__ cnorm, float* __restrict__ idx_out,
    float* __restrict__ qout, float* __restrict__ msd_acc)
{
    __shared__ unsigned short a_bf[64*256];   // 32 KB, swizzled bf16 F-tile
    __shared__ unsigned short b_bf[128*256];  // 64 KB, swizzled bf16 CB-chunk
    __shared__ float cn_s[128];
    __shared__ float red_v[64*64];            // top-2 per (row, entry); reused for msd reduce
    __shared__ int   red_i[64*64];
    __shared__ int   bests[64];
    __shared__ int   cand[64][12];
    __shared__ int   ccnt[64];
    const int tid = threadIdx.x;
    const int m0 = blockIdx.x * 64;

    // ---- stage A once: F[m0..m0+64) x 256 -> bf16, swizzled ----
    #pragma unroll
    for (int u = 0; u < 4; u++) {
        int e = tid + u*512;                 // < 2048
        int row = e >> 5, c = e & 31;
        const float* src = &F[(size_t)(m0+row)*NDCB + c*8];
        float4 f0 = *(const float4*)src;
        float4 f1 = *(const float4*)(src+4);
        u16x8 p;
        p[0]=f2bf(f0.x); p[1]=f2bf(f0.y); p[2]=f2bf(f0.z); p[3]=f2bf(f0.w);
        p[4]=f2bf(f1.x); p[5]=f2bf(f1.y); p[6]=f2bf(f1.z); p[7]=f2bf(f1.w);
        *(u16x8*)((char*)a_bf + row*512 + ((c*16) ^ ((row&7)<<4))) = p;
    }

    // wave w: rows 16*(w&3), cols 64*(w>>2) of each 64x128 chunk
    const int w = tid >> 6, lane = tid & 63;
    const int l15 = lane & 15, kg = lane >> 4;
    const int rbase = (w & 3) << 4, cbase = (w >> 2) << 6;
    const char* aP = (const char*)a_bf + (size_t)(rbase + l15)*512;
    const char* bP = (const char*)b_bf + (size_t)(cbase + l15)*512;
    const int swz = (lane & 7) << 4;

    float mv1[4], mv2[4]; int mi1[4], mi2[4];
    #pragma unroll
    for (int i = 0; i < 4; i++) { mv1[i]=3.0e38f; mv2[i]=3.0e38f; mi1[i]=0x7fffffff; mi2[i]=0x7fffffff; }

    for (int n0 = 0; n0 < NKCB; n0 += 128) {
        __syncthreads();                      // previous chunk's MFMA reads done
        #pragma unroll
        for (int u = 0; u < 8; u++) {
            int e = tid + u*512;              // < 4096
            int row = e >> 5, c = e & 31;
            u16x8 v = *(const u16x8*)&CBH[(size_t)(n0+row)*NDCB + c*8];
            *(u16x8*)((char*)b_bf + row*512 + ((c*16) ^ ((row&7)<<4))) = v;
        }
        if (tid < 128) cn_s[tid] = cnorm[n0 + tid];
        __syncthreads();
        f32x4 acc[4] = {{0.f,0.f,0.f,0.f},{0.f,0.f,0.f,0.f},{0.f,0.f,0.f,0.f},{0.f,0.f,0.f,0.f}};
        #pragma unroll
        for (int kt = 0; kt < 8; kt++) {
            const int ko = (kt*64 + kg*16) ^ swz;
            bf16x8 av = *(const bf16x8*)(aP + ko);
            #pragma unroll
            for (int f = 0; f < 4; f++) {
                bf16x8 bv = *(const bf16x8*)(bP + f*8192 + ko);
                acc[f] = __builtin_amdgcn_mfma_f32_16x16x32_bf16(av, bv, acc[f], 0, 0, 0);
            }
        }
        // epilogue: s = cn - 2*dot ; per-lane top-2.  C layout: col=lane&15, row=(lane>>4)*4+reg.
        #pragma unroll
        for (int f = 0; f < 4; f++) {
            const int col = n0 + cbase + f*16 + l15;
            const float cnv = cn_s[cbase + f*16 + l15];
            #pragma unroll
            for (int i = 0; i < 4; i++) {
                float s = fmaf(-2.0f, acc[f][i], cnv);
                if (s < mv1[i]) { mv2[i]=mv1[i]; mi2[i]=mi1[i]; mv1[i]=s; mi1[i]=col; }
                else if (s < mv2[i]) { mv2[i]=s; mi2[i]=col; }
            }
        }
    }
    #pragma unroll
    for (int i = 0; i < 4; i++) {
        const int row = rbase + kg*4 + i;
        const int eb  = (w>>2)*32 + l15*2;
        red_v[row*64 + eb]   = mv1[i]; red_i[row*64 + eb]   = mi1[i];
        red_v[row*64 + eb+1] = mv2[i]; red_i[row*64 + eb+1] = mi2[i];
    }
    __syncthreads();
    if (tid < 64) {
        float bv = 3.0e38f; int bi = 0x7fffffff;
        for (int e = 0; e < 64; e++) {
            float v = red_v[tid*64 + e]; int ii = red_i[tid*64 + e];
            if (v < bv || (v == bv && ii < bi)) { bv = v; bi = ii; }
        }
        int cnt = 0;
        for (int e = 0; e < 64; e++) {
            if (red_v[tid*64 + e] < bv + 1.0e-5f) {
                if (cnt < 12) cand[tid][cnt] = red_i[tid*64 + e];
                cnt++;
            }
        }
        bests[tid] = bi;
        ccnt[tid] = (cnt > 12) ? 12 : cnt;
    }
    __syncthreads();
    // Canonical fp32-quantized rescore of near-tie rows (one wave per row, round-robin).
    {
        const int wid = tid >> 6, lane2 = tid & 63;
        for (int r = wid; r < 64; r += 8) {
            const int nc = ccnt[r];
            if (nc < 2) continue;
            double sf = 0.0;
            #pragma unroll
            for (int u = 0; u < 4; u++) {
                double fv = (double)F[(size_t)(m0+r)*NDCB + lane2*4 + u];
                sf = fma(fv, fv, sf);
            }
            #pragma unroll
            for (int off = 32; off > 0; off >>= 1) sf += __shfl_down(sf, off);
            const float sf32 = (float)sf;          // valid on lane 0
            float bd2 = 0.0f; int bidx = 0x7fffffff;
            for (int c = 0; c < nc; c++) {
                const int k = cand[r][c];
                double g = 0.0;
                #pragma unroll
                for (int u = 0; u < 4; u++) {
                    double cv = (double)CB[(size_t)k*NDCB + lane2*4 + u];
                    double fv = (double)F[(size_t)(m0+r)*NDCB + lane2*4 + u];
                    g = fma(cv, fv, g);
                }
                #pragma unroll
                for (int off = 32; off > 0; off >>= 1) g += __shfl_down(g, off);
                if (lane2 == 0) {
                    const float G32 = (float)g;
                    const float t  = sf32 - 2.0f*G32;
                    const float d2 = t + cnorm[k];
                    if (c == 0 || d2 < bd2 || (d2 == bd2 && k < bidx)) { bd2 = d2; bidx = k; }
                }
            }
            if (lane2 == 0) bests[r] = bidx;
        }
    }
    __syncthreads();
    if (tid < 64) idx_out[m0 + tid] = (float)bests[tid];
    float lsum = 0.0f;
    #pragma unroll
    for (int s = 0; s < 8; s++) {
        int e = tid + s*512;
        int row = e >> 6, kqe = (e & 63) << 2;
        float4 q = *(const float4*)&CB[(size_t)bests[row]*NDCB + kqe];
        float4 f = *(const float4*)&F[(size_t)(m0+row)*NDCB + kqe];
        float dx=f.x-q.x, dy=f.y-q.y, dz=f.z-q.z, dw=f.w-q.w;
        lsum += dx*dx + dy*dy + dz*dz + dw*dw;
        *(float4*)&qout[(size_t)(m0+row)*NDCB + kqe] = q;
    }
    red_v[tid] = lsum;
    __syncthreads();
    for (int off = 256; off > 0; off >>= 1) {
        if (tid < off) red_v[tid] += red_v[tid + off];
        __syncthreads();
    }
    if (tid == 0) atomicAdd(msd_acc, red_v[0]);
}

// ---------------- xproj: f16 MFMA GEMM (feeds GRU/context_loss, 2% threshold) ----------------
__global__ __launch_bounds__(512) void xproj_mfma_kernel(
    const float* __restrict__ Q, const unsigned short* __restrict__ WIHH,
    const float* __restrict__ bias, float* __restrict__ C)
{
    __shared__ unsigned short a_h[64*256];    // 32 KB, swizzled f16 (q * 8192)
    __shared__ unsigned short b_h[128*256];   // 64 KB, swizzled f16 wih chunk
    const int tid = threadIdx.x;
    const int m0 = blockIdx.x * 64;

    #pragma unroll
    for (int u = 0; u < 4; u++) {
        int e = tid + u*512;                 // < 2048
        int row = e >> 5, c = e & 31;
        const float* src = &Q[(size_t)(m0+row)*NDCB + c*8];
        float4 f0 = *(const float4*)src;
        float4 f1 = *(const float4*)(src+4);
        f16x8 p;
        p[0]=(_Float16)(f0.x*8192.0f); p[1]=(_Float16)(f0.y*8192.0f);
        p[2]=(_Float16)(f0.z*8192.0f); p[3]=(_Float16)(f0.w*8192.0f);
        p[4]=(_Float16)(f1.x*8192.0f); p[5]=(_Float16)(f1.y*8192.0f);
        p[6]=(_Float16)(f1.z*8192.0f); p[7]=(_Float16)(f1.w*8192.0f);
        *(f16x8*)((char*)a_h + row*512 + ((c*16) ^ ((row&7)<<4))) = p;
    }

    const int w = tid >> 6, lane = tid & 63;
    const int l15 = lane & 15, kg = lane >> 4;
    const int rbase = (w & 3) << 4, cbase = (w >> 2) << 6;
    const char* aP = (const char*)a_h + (size_t)(rbase + l15)*512;
    const char* bP = (const char*)b_h + (size_t)(cbase + l15)*512;
    const int swz = (lane & 7) << 4;

    for (int n0 = 0; n0 < 768; n0 += 128) {
        __syncthreads();
        #pragma unroll
        for (int u = 0; u < 8; u++) {
            int e = tid + u*512;              // < 4096
            int row = e >> 5, c = e & 31;
            u16x8 v = *(const u16x8*)&WIHH[(size_t)(n0+row)*NDCB + c*8];
            *(u16x8*)((char*)b_h + row*512 + ((c*16) ^ ((row&7)<<4))) = v;
        }
        __syncthreads();
        f32x4 acc[4] = {{0.f,0.f,0.f,0.f},{0.f,0.f,0.f,0.f},{0.f,0.f,0.f,0.f},{0.f,0.f,0.f,0.f}};
        #pragma unroll
        for (int kt = 0; kt < 8; kt++) {
            const int ko = (kt*64 + kg*16) ^ swz;
            f16x8 av = *(const f16x8*)(aP + ko);
            #pragma unroll
            for (int f = 0; f < 4; f++) {
                f16x8 bv = *(const f16x8*)(bP + f*8192 + ko);
                acc[f] = __builtin_amdgcn_mfma_f32_16x16x32_f16(av, bv, acc[f], 0, 0, 0);
            }
        }
        // C layout: col=lane&15, row=(lane>>4)*4+reg
        #pragma unroll
        for (int f = 0; f < 4; f++) {
            const int col = n0 + cbase + f*16 + l15;
            const float bv = bias[col];
            #pragma unroll
            for (int i = 0; i < 4; i++) {
                const int row = m0 + rbase + kg*4 + i;
                C[(size_t)row*768 + col] = fmaf(acc[f][i], 1.0f/8192.0f, bv);
            }
        }
    }
}

// ---------------- GRU scan: 512 threads/batch, f16 whh (proven gru_c, ~655us) ----------------
// FINAL after 7 rounds of experiments: the backend refuses >128 arch-VGPR at any thread count
// (spill replay ~3050 cyc/step = the 655us).  All structural alternatives have floors within
// ~15% of this: multi-CU splits need per-step cross-XCD exchange (>=0.4-1us x 511 steps);
// single-block LDS/L2/fp8 mixes are walled by per-CU L2 BW (~92B/cyc) or fp8-decode VALU.
// gru_c is ~at the achievable floor for this recurrence shape on this chip.
__global__ __launch_bounds__(512)
void gru_c(const float* __restrict__ XP, const float* __restrict__ WHH,
           const float* __restrict__ bhh, const float* __restrict__ F,
           float* __restrict__ ctx_acc)
{
    __shared__ float part[3][2][256];
    __shared__ uint4 hpk[2][32];
    __shared__ float red[256];
    const int tid = threadIdx.x;
    const int b = blockIdx.x;
    const int j = tid & 255;
    const int q = tid >> 8;           // 0..1
    half2_t wr[64], wz[64], wn[64];
    {
        const float* rp = WHH + (size_t)j*256 + q*128;
        #pragma unroll
        for (int k = 0; k < 32; k++) {
            float4 vr = *(const float4*)(rp + 4*k);
            float4 vz = *(const float4*)(rp + 65536 + 4*k);
            float4 vn = *(const float4*)(rp + 131072 + 4*k);
            wr[2*k+0] = (half2_t){(_Float16)vr.x, (_Float16)vr.y};
            wr[2*k+1] = (half2_t){(_Float16)vr.z, (_Float16)vr.w};
            wz[2*k+0] = (half2_t){(_Float16)vz.x, (_Float16)vz.y};
            wz[2*k+1] = (half2_t){(_Float16)vz.z, (_Float16)vz.w};
            wn[2*k+0] = (half2_t){(_Float16)vn.x, (_Float16)vn.y};
            wn[2*k+1] = (half2_t){(_Float16)vn.z, (_Float16)vn.w};
        }
    }
    if (tid < 64) hpk[tid >> 5][tid & 31] = make_uint4(0u, 0u, 0u, 0u);
    const float bb0 = bhh[j], bb1 = bhh[256+j], bb2 = bhh[512+j];
    const float* xpb = XP + (size_t)b*NT*768;
    const float* fb  = F  + (size_t)b*NT*NDCB;
    float hprev = 0.0f, lsum = 0.0f;
    __syncthreads();
    int cur = 0;
    for (int t = 0; t < NT-1; t++) {
        float xr = 0.f, xz = 0.f, xn = 0.f, fv = 0.f;
        if (tid < 256) {
            const float* xp = xpb + (size_t)t*768;
            xr = xp[j]; xz = xp[256+j]; xn = xp[512+j];
            fv = fb[(size_t)(t+1)*NDCB + j];
        }
        float a0=0.f, c0=0.f, a1=0.f, c1=0.f, a2=0.f, c2=0.f;
        #pragma unroll
        for (int kk = 0; kk < 16; kk++) {
            uint4 hp = hpk[cur][q*16 + kk];
            half2_t h0 = h2of(hp.x), h1 = h2of(hp.y), h2 = h2of(hp.z), h3 = h2of(hp.w);
            a0 = dot2f(wr[4*kk+0], h0, a0); c0 = dot2f(wr[4*kk+1], h1, c0);
            a1 = dot2f(wz[4*kk+0], h0, a1); c1 = dot2f(wz[4*kk+1], h1, c1);
            a2 = dot2f(wn[4*kk+0], h0, a2); c2 = dot2f(wn[4*kk+1], h1, c2);
            a0 = dot2f(wr[4*kk+2], h2, a0); c0 = dot2f(wr[4*kk+3], h3, c0);
            a1 = dot2f(wz[4*kk+2], h2, a1); c1 = dot2f(wz[4*kk+3], h3, c1);
            a2 = dot2f(wn[4*kk+2], h2, a2); c2 = dot2f(wn[4*kk+3], h3, c2);
        }
        part[0][q][j] = a0 + c0; part[1][q][j] = a1 + c1; part[2][q][j] = a2 + c2;
        __syncthreads();
        if (tid < 256) {
            float ghr = part[0][0][j] + part[0][1][j] + bb0;
            float ghz = part[1][0][j] + part[1][1][j] + bb1;
            float ghn = part[2][0][j] + part[2][1][j] + bb2;
            float r = 1.0f/(1.0f + __expf(-(xr + ghr)));
            float z = 1.0f/(1.0f + __expf(-(xz + ghz)));
            float v = fmaf(r, ghn, xn);
            v = fminf(fmaxf(v, -12.0f), 12.0f);
            float ev = __expf(-2.0f*v);
            float n = (1.0f - ev)/(1.0f + ev);
            float hnew = (1.0f - z)*n + z*hprev;
            float d = hnew - fv;
            lsum = fmaf(d, d, lsum);
            float nb = __shfl_down(hnew, 1);
            if (!(j & 1)) {
                half2_t p; p[0] = (_Float16)hnew; p[1] = (_Float16)nb;
                ((unsigned int*)&hpk[cur ^ 1][0])[j >> 1] = __builtin_bit_cast(unsigned int, p);
            }
            hprev = hnew;
        }
        __syncthreads();
        cur ^= 1;
    }
    if (tid < 256) red[j] = lsum;
    __syncthreads();
    for (int off = 128; off > 0; off >>= 1) {
        if (tid < off) red[tid] += red[tid + off];
        __syncthreads();
    }
    if (tid == 0) atomicAdd(ctx_acc, red[0]);
}

// ---------------- small prep kernels ----------------
__global__ __launch_bounds__(256) void prep_kernel(
    const float* __restrict__ conv_w, float* __restrict__ w3,
    const float* __restrict__ wih, unsigned short* __restrict__ wihh,
    float* __restrict__ accv)
{
    int e = blockIdx.x*256 + threadIdx.x;     // < 196608
    if (e == 0) { accv[0] = 0.0f; accv[1] = 0.0f; }
    {   // w3[k][c][i] = conv_w[c][i][k]
        int k = e >> 16;
        int r = e & 65535;
        int c = r >> 8, i = r & 255;
        w3[e] = conv_w[(size_t)c*768 + i*3 + k];
    }
    {   // wih f32 -> f16 bits (768*256 = 196608 elements, exactly this grid)
        _Float16 h = (_Float16)wih[e];
        wihh[e] = __builtin_bit_cast(unsigned short, h);
    }
}

// codebook fp32 -> bf16 (RNE), for the MFMA prefilter
__global__ __launch_bounds__(256) void cb2bf_kernel(
    const float* __restrict__ cb, unsigned short* __restrict__ cbh)
{
    int e = (blockIdx.x*256 + threadIdx.x) * 4;   // 2,097,152 elems / 4
    float4 v = *(const float4*)&cb[e];
    unsigned short p0 = f2bf(v.x), p1 = f2bf(v.y), p2 = f2bf(v.z), p3 = f2bf(v.w);
    unsigned long long pk = (unsigned long long)p0 | ((unsigned long long)p1 << 16)
                          | ((unsigned long long)p2 << 32) | ((unsigned long long)p3 << 48);
    *(unsigned long long*)&cbh[e] = pk;
}

// s_c = fl32(exact sum c^2) via fp64   [LOCKED numerics]
__global__ __launch_bounds__(64) void cnorm_kernel(
    const float* __restrict__ CB, float* __restrict__ cn)
{
    const int k = blockIdx.x;
    const int lane = threadIdx.x;
    float4 v = *(const float4*)&CB[(size_t)k*NDCB + lane*4];
    double s = (double)v.x*(double)v.x + (double)v.y*(double)v.y
             + (double)v.z*(double)v.z + (double)v.w*(double)v.w;
    #pragma unroll
    for (int off = 32; off > 0; off >>= 1) s += __shfl_down(s, off);
    if (lane == 0) cn[k] = (float)s;
}

__global__ void finalize_kernel(const float* __restrict__ acc, float* __restrict__ out)
{
    if (threadIdx.x == 0) {
        float msd = acc[0] * (1.0f/4194304.0f);   // mean over 32*512*256
        float ctx = acc[1] * (1.0f/4184064.0f);   // mean over 32*511*256
        out[0] = msd;                 // commitment_loss
        out[1] = msd;                 // codebook_loss (same forward value)
        out[2] = ctx;                 // context_loss
        out[3] = 1.25f*msd + 0.1f*ctx; // vq_loss
    }
}

extern "C" void kernel_launch(void* const* d_in, const int* in_sizes, int n_in,
                              void* d_out, int out_size, void* d_ws, size_t ws_size,
                              hipStream_t stream) {
    const float* x      = (const float*)d_in[0];
    const float* w1     = (const float*)d_in[1];
    const float* b1     = (const float*)d_in[2];
    const float* w2     = (const float*)d_in[3];
    const float* b2     = (const float*)d_in[4];
    const float* conv_w = (const float*)d_in[5];
    const float* conv_b = (const float*)d_in[6];
    const float* cb     = (const float*)d_in[7];
    const float* wih    = (const float*)d_in[8];
    const float* whh    = (const float*)d_in[9];
    const float* bih    = (const float*)d_in[10];
    const float* bhh    = (const float*)d_in[11];
    float* out = (float*)d_out;

    // workspace layout (regions re-used once dead):
    //   [0,        16.7M)  feat  (fp32)          conv -> gru
    //   [16.7M,    50.3M)  h1    (fp32)          gemm1 -> gemm2
    //   [16.7M,    67.1M)  xproj (fp32, 50.3MB)  gemm3 -> gru   (overlays dead h1+h2)
    //   [50.3M,    67.1M)  h2    (fp32)          gemm2 -> conv
    //   [50.3M,    54.5M)  cbh   (bf16, 4MB)     cb2bf -> vq    (overlays dead h2)
    //   [67.1M, ...]       cn / w3 / wihh / accv
    char* ws = (char*)d_ws;
    float*  feat   = (float*)(ws + 0);
    float*  h1     = (float*)(ws + 16777216);
    float*  xproj  = (float*)(ws + 16777216);
    float*  h2     = (float*)(ws + 50331648);
    unsigned short* cbh = (unsigned short*)(ws + 50331648);
    float*  cn     = (float*)(ws + 67108864);
    float*  w3     = (float*)(ws + 67141632);
    unsigned short* wihh = (unsigned short*)(ws + 67928064);   // 393216 B
    float*  accv   = (float*)(ws + 68714496);

    float* idx_out = out;                   // 16384 indices (as float)
    float* qout    = out + 16384;           // 4,194,304 quantized
    float* louts   = out + 16384 + 4194304; // 4 scalars

    prep_kernel<<<768, 256, 0, stream>>>(conv_w, w3, wih, wihh, accv);
    cnorm_kernel<<<NKCB, 64, 0, stream>>>(cb, cn);
    gemm_nt_f64_kernel<true ><<<dim3(NHMID/64, NROWS/64), 256, 0, stream>>>(x,  w1, b1, h1, NROWS, NHMID, NDIN);
    gemm_nt_f64_kernel<true ><<<dim3(NDCB/64,  NROWS/64), 256, 0, stream>>>(h1, w2, b2, h2, NROWS, NDCB, NHMID);
    conv3_f64_kernel<<<dim3(NDCB/64, NROWS/64), 256, 0, stream>>>(h2, w3, conv_b, feat);
    cb2bf_kernel<<<2048, 256, 0, stream>>>(cb, cbh);   // after conv3: overlays dead h2
    vq_kernel<<<NROWS/64, 512, 0, stream>>>(feat, cb, cbh, cn, idx_out, qout, accv);
    xproj_mfma_kernel<<<NROWS/64, 512, 0, stream>>>(qout, wihh, bih, xproj);
    gru_c<<<NB, 512, 0, stream>>>(xproj, whh, bhh, feat, accv + 1);
    finalize_kernel<<<1, 64, 0, stream>>>(accv, louts);
}